// Round 10
// baseline (4218.352 us; speedup 1.0000x reference)
//
#include <hip/hip_runtime.h>
#include <hip/hip_fp16.h>
#include <cstddef>

using half_t = __half;
typedef __attribute__((ext_vector_type(8))) _Float16 f16x8;
typedef __attribute__((ext_vector_type(4))) float f32x4;

#define T_SEQ 512
#define B_SZ  128
#define H_SZ  200
#define D_EMB 50
#define K0P   64    // layer-0 K padded (50 -> 64)
#define K_TAGS 25
#define HA_S 232   // hA row stride (halfs)
#define GL_S 204   // gl row stride (halfs)

__device__ __forceinline__ float sigf(float x) {
  return __builtin_amdgcn_rcpf(1.f + __expf(-x));   // NaN-free at +-inf
}
__device__ __forceinline__ float tanf_(float x) {
  return 1.f - 2.f * __builtin_amdgcn_rcpf(__expf(2.f * x) + 1.f);  // NaN-free
}

// x0 strided K0P with zero pad: x0[(t*128+b)*64 + d]
__global__ __launch_bounds__(256) void embed_kernel(const int* __restrict__ x,
                                                    const float* __restrict__ emb,
                                                    half_t* __restrict__ x0) {
  int idx = blockIdx.x * 256 + threadIdx.x;
  if (idx >= T_SEQ * B_SZ * K0P) return;
  int d  = idx & (K0P - 1);
  int tb = idx >> 6;
  int b  = tb % B_SZ;
  int t  = tb / B_SZ;
  float v = 0.f;
  if (d < D_EMB) {
    int tok = x[b * T_SEQ + t];
    v = emb[(size_t)tok * D_EMB + d];
  }
  x0[idx] = __float2half(v);
}

__global__ __launch_bounds__(256) void bsum_kernel(const float* __restrict__ b0,
                                                   const float* __restrict__ b1,
                                                   float* __restrict__ bsum) {
  int i = blockIdx.x * 256 + threadIdx.x;
  if (i >= 3200) return;
  const float* src = (i < 1600) ? b0 : b1;
  int j = (i < 1600) ? i : (i - 1600);
  int dir = j / 800, g = j % 800;
  bsum[i] = src[dir * 1600 + g] + src[dir * 1600 + 800 + g];
}

__global__ __launch_bounds__(256) void zero_kernel(float* __restrict__ p, int n) {
  int i = blockIdx.x * 256 + threadIdx.x;
  if (i < n) p[i] = 0.f;
}

// generic fp32->fp16 pad-convert: dst[r][k] (Rdst x Kdst) from src (Rsrc x Ksrc)
__global__ __launch_bounds__(256) void conv_pad_kernel(const float* __restrict__ src,
                                                       half_t* __restrict__ dst,
                                                       int Rsrc, int Ksrc, int Kdst, int n) {
  int i = blockIdx.x * 256 + threadIdx.x;
  if (i >= n) return;
  int k = i % Kdst, r = i / Kdst;
  float v = (r < Rsrc && k < Ksrc) ? src[(size_t)r * Ksrc + k] : 0.f;
  dst[i] = __float2half(v);
}

// Whh -> MFMA A-operand fragments, fp16: dst[d][tt<50][kt<7][lane<64][i<8]
// frag element: n = tt*16 + (lane&15), k = kt*32 + (lane>>4)*8 + i  (0 if k>=200)
__global__ __launch_bounds__(256) void conv_wfrag_kernel(const float* __restrict__ whh,
                                                         half_t* __restrict__ dst) {
  int idx = blockIdx.x * 256 + threadIdx.x;
  if (idx >= 2 * 50 * 7 * 512) return;
  int i8   = idx & 7;
  int lane = (idx >> 3) & 63;
  int kt   = (idx >> 9) % 7;
  int tmp  = (idx >> 9) / 7;      // d*50 + tt
  int tt   = tmp % 50, d = tmp / 50;
  int n = tt * 16 + (lane & 15);
  int k = kt * 32 + (lane >> 4) * 8 + i8;
  float v = (k < H_SZ) ? whh[((size_t)d * 800 + n) * H_SZ + k] : 0.f;
  dst[idx] = __float2half(v);
}

// MFMA xw GEMM for one time-chunk. Grid (13 n-tiles, 2*C dirTq, 2 b-half), 256 thr.
// chunk layout (fp16): [sc][dir][b][j][gate]. K % 8 == 0 required (padded).
__global__ __launch_bounds__(256) void xw_mfma_kernel(const half_t* __restrict__ A,
                                                      const half_t* __restrict__ Wh,
                                                      const float* __restrict__ bsumL,
                                                      half_t* __restrict__ chunk,
                                                      int K, int C, int q) {
  __shared__ __align__(16) unsigned short As[64][40];
  __shared__ __align__(16) unsigned short Bs[64][40];
  const int tid = threadIdx.x;
  const int w = tid >> 6, lane = tid & 63;
  const int col = lane & 15, quad = lane >> 4;
  const int dirTq = blockIdx.y;
  const int dir = dirTq / C;
  const int tq  = dirTq - dir * C;
  const int t = dir ? (T_SEQ - 1 - q * C - tq) : (q * C + tq);
  const int n0 = blockIdx.x * 64;
  const int z = blockIdx.z;
  const size_t Arow0 = (size_t)t * B_SZ + z * 64;
  f32x4 acc[4];
#pragma unroll
  for (int c = 0; c < 4; ++c) acc[c] = (f32x4){0.f, 0.f, 0.f, 0.f};

  const int nkb = (K + 31) / 32;
  for (int kb = 0; kb < nkb; ++kb) {
    const int k0 = kb * 32;
    int row = tid >> 2, seg = tid & 3;
    int k = k0 + seg * 8;
    uint4 va = (k < K) ? *(const uint4*)&A[(Arow0 + row) * K + k]
                       : make_uint4(0, 0, 0, 0);
    *(uint4*)&As[row][seg * 8] = va;
    int n = n0 + row;
    uint4 vb = (k < K && n < 800) ? *(const uint4*)&Wh[((size_t)dir * 800 + n) * K + k]
                                  : make_uint4(0, 0, 0, 0);
    *(uint4*)&Bs[row][seg * 8] = vb;
    __syncthreads();
    f16x8 af = *(const f16x8*)&As[w * 16 + col][quad * 8];
#pragma unroll
    for (int c = 0; c < 4; ++c) {
      f16x8 bf = *(const f16x8*)&Bs[c * 16 + col][quad * 8];
      acc[c] = __builtin_amdgcn_mfma_f32_16x16x32_f16(af, bf, acc[c], 0, 0, 0);
    }
    __syncthreads();
  }

#pragma unroll
  for (int c = 0; c < 4; ++c) {
    int n = n0 + c * 16 + col;
    if (n < 800) {
      float bia = bsumL[dir * 800 + n];
      int g = n / 200, j = n - g * 200;
#pragma unroll
      for (int r = 0; r < 4; ++r) {
        int brow = z * 64 + w * 16 + quad * 4 + r;
        size_t idx = ((((size_t)tq * 2 + dir) * B_SZ + brow) * H_SZ + j) * 4 + g;
        chunk[idx] = __float2half(acc[c][r] + bia);
      }
    }
  }
}

// Weight-resident no-sync recurrence, v4: 1024 thr (16 waves) so the per-wave
// weight share (3 tiles = 84 VGPRs) plus working set fits the honest 128-VGPR
// budget at 16 waves/CU. Tiles 48,49 + gl + hA in LDS (48 KB). The empty-asm
// "+v" pin each step makes the weight frags loop-carried: the allocator cannot
// rematerialize them from global (R8/R9: it re-streamed 256 KB/step from L2).
__global__ __launch_bounds__(1024, 4) void persist4_kernel(
    const half_t* __restrict__ chunk,     // [sc][d][b][j][g] fp16
    const half_t* __restrict__ wfragG,    // [d][50][7][64][8] fp16
    float* __restrict__ hslab,            // [d][128][200] fp32 (chunk-boundary h)
    float* __restrict__ cslab,            // [d][128][200] fp32
    half_t* __restrict__ hbuf,            // [t][128][400] fp16
    int q, int C) {
  const int tid = threadIdx.x;
  const int wv = tid >> 6, lane = tid & 63;
  const int col = lane & 15, quad = lane >> 4;
  const int bt = blockIdx.x, d = blockIdx.y;
  const int bg0 = bt * 16;

  __shared__ __align__(16) unsigned short wlds[2 * 7 * 512];   // 14336 B
  __shared__ __align__(16) unsigned short gl[4 * 16 * GL_S];   // 26112 B
  __shared__ __align__(16) unsigned short hA[16 * HA_S];       // 7424 B

  const unsigned short* wfG = (const unsigned short*)wfragG;

  // 48 tiles resident in VGPRs (3/wave: tt = wv, wv+16, wv+32)
  f16x8 wfrag[3][7];
#pragma unroll
  for (int u = 0; u < 3; ++u) {
    int tt = wv + 16 * u;
#pragma unroll
    for (int kt = 0; kt < 7; ++kt)
      wfrag[u][kt] = *(const f16x8*)&wfG[(((size_t)d * 50 + tt) * 7 + kt) * 512 + lane * 8];
  }
  // tiles 48,49 -> LDS (linear copy of 896 uint4)
  if (tid < 896)
    *(uint4*)&wlds[tid * 8] =
        *(const uint4*)&wfG[((size_t)d * 50 + 48) * 7 * 512 + (size_t)tid * 8];

  // h init (fp32 -> fp16, zero k-pad)
  for (int i = tid; i < 16 * HA_S; i += 1024) {
    int m = i / HA_S, k = i - m * HA_S;
    float v = (k < H_SZ) ? hslab[((size_t)d * B_SZ + bg0 + m) * H_SZ + k] : 0.f;
    hA[i] = __half_as_ushort(__float2half(v));
  }
  // c init (1600 (b, j-pair) items over 1024 threads)
  float2 creg[2];
#pragma unroll
  for (int it = 0; it < 2; ++it) {
    int p = it * 1024 + tid;
    if (p < 1600) {
      int b = p / 100, j = (p - b * 100) * 2;
      creg[it] = *(const float2*)&cslab[((size_t)d * B_SZ + bg0 + b) * H_SZ + j];
    } else creg[it] = make_float2(0.f, 0.f);
  }
  __syncthreads();

  for (int sc = 0; sc < C; ++sc) {
    // pin weight frags: loop-carried, cannot be rematerialized from memory
#pragma unroll
    for (int u = 0; u < 3; ++u)
#pragma unroll
      for (int kt = 0; kt < 7; ++kt)
        asm volatile("" : "+v"(wfrag[u][kt]));

    const int sg = q * C + sc;
    const int t = d ? (T_SEQ - 1 - sg) : sg;

    // prefetch xw pre-activations (HBM latency hidden under MFMA phase)
    f16x8 cpre[2];
#pragma unroll
    for (int it = 0; it < 2; ++it) {
      int p = it * 1024 + tid;
      if (p < 1600) {
        int b = p / 100, j = (p - b * 100) * 2;
        cpre[it] = *(const f16x8*)&chunk[((((size_t)sc * 2 + d) * B_SZ + bg0 + b) * H_SZ + j) * 4];
      }
    }

    f32x4 acc0 = (f32x4){0.f, 0.f, 0.f, 0.f};
    f32x4 acc1 = acc0, acc2 = acc0, acc3 = acc0;
#pragma unroll
    for (int kt = 0; kt < 7; ++kt) {
      f16x8 hf = *(const f16x8*)&hA[col * HA_S + kt * 32 + quad * 8];
      acc0 = __builtin_amdgcn_mfma_f32_16x16x32_f16(wfrag[0][kt], hf, acc0, 0, 0, 0);
      acc1 = __builtin_amdgcn_mfma_f32_16x16x32_f16(wfrag[1][kt], hf, acc1, 0, 0, 0);
      acc2 = __builtin_amdgcn_mfma_f32_16x16x32_f16(wfrag[2][kt], hf, acc2, 0, 0, 0);
      if (wv < 2) {
        f16x8 wf3 = *(const f16x8*)&wlds[(wv * 7 + kt) * 512 + lane * 8];
        acc3 = __builtin_amdgcn_mfma_f32_16x16x32_f16(wf3, hf, acc3, 0, 0, 0);
      }
    }
    // store gates (n4 is 4-aligned; gate boundary 200 is 4-aligned -> no split)
#pragma unroll
    for (int u = 0; u < 3; ++u) {
      f32x4 a = (u == 0) ? acc0 : (u == 1) ? acc1 : acc2;
      int tt = wv + 16 * u;
      int n4 = tt * 16 + quad * 4;
      int g = n4 / 200, j0 = n4 - g * 200;
      union { __half2 h2[2]; uint2 u2; } pk;
      pk.h2[0] = __floats2half2_rn(a[0], a[1]);
      pk.h2[1] = __floats2half2_rn(a[2], a[3]);
      *(uint2*)&gl[(g * 16 + col) * GL_S + j0] = pk.u2;
    }
    if (wv < 2) {
      int n4 = (48 + wv) * 16 + quad * 4;   // 768..799 -> g=3, j0=n4-600
      int j0 = n4 - 600;
      union { __half2 h2[2]; uint2 u2; } pk;
      pk.h2[0] = __floats2half2_rn(acc3[0], acc3[1]);
      pk.h2[1] = __floats2half2_rn(acc3[2], acc3[3]);
      *(uint2*)&gl[(3 * 16 + col) * GL_S + j0] = pk.u2;
    }
    __syncthreads();

    // epilogue into registers + hA; global stores deferred past the barrier
    unsigned int hst[2];
#pragma unroll
    for (int it = 0; it < 2; ++it) {
      int p = it * 1024 + tid;
      if (p < 1600) {
        int b = p / 100, j = (p - b * 100) * 2;
        __half2 r0 = *(const __half2*)&gl[(0 * 16 + b) * GL_S + j];
        __half2 r1 = *(const __half2*)&gl[(1 * 16 + b) * GL_S + j];
        __half2 r2 = *(const __half2*)&gl[(2 * 16 + b) * GL_S + j];
        __half2 r3 = *(const __half2*)&gl[(3 * 16 + b) * GL_S + j];
        float i0 = sigf((float)cpre[it][0] + __low2float(r0));
        float f0 = sigf((float)cpre[it][1] + __low2float(r1));
        float g0 = tanf_((float)cpre[it][2] + __low2float(r2));
        float o0 = sigf((float)cpre[it][3] + __low2float(r3));
        float i1 = sigf((float)cpre[it][4] + __high2float(r0));
        float f1 = sigf((float)cpre[it][5] + __high2float(r1));
        float g1 = tanf_((float)cpre[it][6] + __high2float(r2));
        float o1 = sigf((float)cpre[it][7] + __high2float(r3));
        float c0 = f0 * creg[it].x + i0 * g0;
        float c1 = f1 * creg[it].y + i1 * g1;
        float h0 = o0 * tanf_(c0);
        float h1 = o1 * tanf_(c1);
        creg[it] = make_float2(c0, c1);
        __half2 hh = __floats2half2_rn(h0, h1);
        *(__half2*)&hA[b * HA_S + j] = hh;
        hst[it] = *(unsigned int*)&hh;
      }
    }
    __syncthreads();
    // deferred global stores: drain overlaps next step's MFMA phase
#pragma unroll
    for (int it = 0; it < 2; ++it) {
      int p = it * 1024 + tid;
      if (p < 1600) {
        int b = p / 100, j = (p - b * 100) * 2;
        *(unsigned int*)&hbuf[((size_t)t * B_SZ + bg0 + b) * 400 + d * H_SZ + j] = hst[it];
      }
    }
  }

  // persist c (fp32) and h (fp16-rounded == what a continuing chunk consumes)
#pragma unroll
  for (int it = 0; it < 2; ++it) {
    int p = it * 1024 + tid;
    if (p < 1600) {
      int b = p / 100, j = (p - b * 100) * 2;
      *(float2*)&cslab[((size_t)d * B_SZ + bg0 + b) * H_SZ + j] = creg[it];
    }
  }
  for (int i = tid; i < 16 * H_SZ; i += 1024) {
    int m = i / H_SZ, k = i - m * H_SZ;
    hslab[((size_t)d * B_SZ + bg0 + m) * H_SZ + k] =
        __half2float(__ushort_as_half(hA[m * HA_S + k]));
  }
}

// emissions via MFMA: em[m][25] = h[m][400] @ lin_w[25][400]^T + lin_b
__global__ __launch_bounds__(256) void emis_mfma_kernel(const half_t* __restrict__ A,
                                                        const half_t* __restrict__ linpad,
                                                        const float* __restrict__ bias,
                                                        float* __restrict__ em) {
  const int tid = threadIdx.x;
  const int wv = tid >> 6, lane = tid & 63;
  const int col = lane & 15, quad = lane >> 4;
  const size_t m0 = (size_t)blockIdx.x * 64 + wv * 16;

  f16x8 wf[2][13];
#pragma unroll
  for (int nt = 0; nt < 2; ++nt)
#pragma unroll
    for (int kt = 0; kt < 13; ++kt)
      wf[nt][kt] = *(const f16x8*)&linpad[(nt * 16 + col) * 416 + kt * 32 + quad * 8];

  f32x4 acc[2];
  acc[0] = (f32x4){0.f, 0.f, 0.f, 0.f};
  acc[1] = (f32x4){0.f, 0.f, 0.f, 0.f};
#pragma unroll
  for (int kt = 0; kt < 13; ++kt) {
    f16x8 hfv = (f16x8)(_Float16)0.f;
    if (kt < 12 || quad < 2)
      hfv = *(const f16x8*)&A[(m0 + col) * 400 + kt * 32 + quad * 8];
    acc[0] = __builtin_amdgcn_mfma_f32_16x16x32_f16(wf[0][kt], hfv, acc[0], 0, 0, 0);
    acc[1] = __builtin_amdgcn_mfma_f32_16x16x32_f16(wf[1][kt], hfv, acc[1], 0, 0, 0);
  }
#pragma unroll
  for (int nt = 0; nt < 2; ++nt)
#pragma unroll
    for (int r = 0; r < 4; ++r) {
      int tag = nt * 16 + quad * 4 + r;
      if (tag < K_TAGS)
        em[(m0 + col) * K_TAGS + tag] = acc[nt][r] + bias[tag];
    }
}

// One wave per batch element; denominator loop is pure register/shuffle.
__global__ __launch_bounds__(64) void crf_kernel(const float* __restrict__ em,
                                                 const int* __restrict__ y,
                                                 const float* __restrict__ start,
                                                 const float* __restrict__ endv,
                                                 const float* __restrict__ trans,
                                                 float* __restrict__ partial) {
  const int b = blockIdx.x;
  const int lane = threadIdx.x;
  __shared__ float tr[K_TAGS * K_TAGS];
  for (int i = lane; i < K_TAGS * K_TAGS; i += 64) tr[i] = trans[i];
  __syncthreads();

  float acc = 0.f;
  for (int t = 1 + lane; t < T_SEQ; t += 64) {
    int yp = y[b * T_SEQ + t - 1];
    int yt = y[b * T_SEQ + t];
    acc += tr[yp * K_TAGS + yt] + em[((size_t)t * B_SZ + b) * K_TAGS + yt];
  }
#pragma unroll
  for (int off = 32; off; off >>= 1) acc += __shfl_down(acc, off);
  float num = 0.f;
  if (lane == 0) {
    int y0 = y[b * T_SEQ];
    int yl = y[b * T_SEQ + T_SEQ - 1];
    num = acc + start[y0] + em[(size_t)b * K_TAGS + y0] + endv[yl];
  }

  const int j = lane;
  float trc[K_TAGS];
#pragma unroll
  for (int i = 0; i < K_TAGS; ++i) trc[i] = (j < K_TAGS) ? tr[i * K_TAGS + j] : 0.f;
  float sc = (j < K_TAGS) ? start[j] + em[(size_t)b * K_TAGS + j] : -1e30f;

  for (int t = 1; t < T_SEQ; ++t) {
    float tmp[K_TAGS];
#pragma unroll
    for (int i = 0; i < K_TAGS; ++i) tmp[i] = __shfl(sc, i) + trc[i];
    float m = tmp[0];
#pragma unroll
    for (int i = 1; i < K_TAGS; ++i) m = fmaxf(m, tmp[i]);
    float s = 0.f;
#pragma unroll
    for (int i = 0; i < K_TAGS; ++i) s += __expf(tmp[i] - m);
    float emt = (j < K_TAGS) ? em[((size_t)t * B_SZ + b) * K_TAGS + j] : 0.f;
    float nv = emt + m + __logf(s);
    sc = (j < K_TAGS) ? nv : -1e30f;
  }

  float v = (j < K_TAGS) ? sc + endv[j] : -1e30f;
  float m = v;
#pragma unroll
  for (int off = 32; off; off >>= 1) m = fmaxf(m, __shfl_xor(m, off));
  float s = __expf(v - m);
#pragma unroll
  for (int off = 32; off; off >>= 1) s += __shfl_xor(s, off);
  if (lane == 0) partial[b] = num - (m + __logf(s));
}

__global__ __launch_bounds__(64) void reduce_kernel(const float* __restrict__ partial,
                                                    float* __restrict__ out) {
  int lane = threadIdx.x;
  float v = partial[lane] + partial[lane + 64];
#pragma unroll
  for (int off = 32; off; off >>= 1) v += __shfl_down(v, off);
  if (lane == 0) out[0] = v;
}

extern "C" void kernel_launch(void* const* d_in, const int* in_sizes, int n_in,
                              void* d_out, int out_size, void* d_ws, size_t ws_size,
                              hipStream_t stream) {
  (void)in_sizes; (void)n_in; (void)out_size;
  const int*   x        = (const int*)d_in[0];
  const int*   y        = (const int*)d_in[1];
  const float* emb      = (const float*)d_in[3];
  const float* w_ih_l0  = (const float*)d_in[4];
  const float* w_hh_l0  = (const float*)d_in[5];
  const float* b_l0     = (const float*)d_in[6];
  const float* w_ih_l1  = (const float*)d_in[7];
  const float* w_hh_l1  = (const float*)d_in[8];
  const float* b_l1     = (const float*)d_in[9];
  const float* lin_w    = (const float*)d_in[10];
  const float* lin_b    = (const float*)d_in[11];
  const float* crf_start= (const float*)d_in[12];
  const float* crf_end  = (const float*)d_in[13];
  const float* crf_trans= (const float*)d_in[14];
  float* out = (float*)d_out;

  char* ws = (char*)d_ws;
  size_t off = 0;
  auto alloc = [&](size_t bytes) {
    size_t r = off;
    off = (off + bytes + 255) & ~(size_t)255;
    return r;
  };
  half_t* x0    = (half_t*)(ws + alloc((size_t)T_SEQ * B_SZ * K0P * 2));
  half_t* hbuf0 = (half_t*)(ws + alloc((size_t)T_SEQ * B_SZ * 400 * 2));
  half_t* hbuf1 = (half_t*)(ws + alloc((size_t)T_SEQ * B_SZ * 400 * 2));
  float*  em    = (float*)(ws + alloc((size_t)T_SEQ * B_SZ * K_TAGS * 4));
  float*  bsum  = (float*)(ws + alloc(3200 * 4));
  half_t* wih0h = (half_t*)(ws + alloc((size_t)1600 * K0P * 2));
  half_t* wih1h = (half_t*)(ws + alloc((size_t)1600 * 400 * 2));
  half_t* wf0   = (half_t*)(ws + alloc((size_t)2 * 50 * 7 * 512 * 2));
  half_t* wf1   = (half_t*)(ws + alloc((size_t)2 * 50 * 7 * 512 * 2));
  half_t* linpad= (half_t*)(ws + alloc((size_t)32 * 416 * 2));
  // contiguous zero region: hslab | cslab
  size_t zOff = off;
  float* hslab = (float*)(ws + alloc((size_t)2 * B_SZ * H_SZ * 4));
  float* cslab = (float*)(ws + alloc((size_t)2 * B_SZ * H_SZ * 4));
  size_t zLen = off - zOff;
  float* partial = (float*)(ws + alloc(B_SZ * 4));
  size_t fixedBytes = off;

  // largest time-chunk that fits (fewer launch boundaries)
  int C = 512;
  while (C > 4 && fixedBytes + (size_t)C * 409600 + (1u << 20) > ws_size) C >>= 1;
  half_t* chunk = (half_t*)(ws + alloc((size_t)2 * C * B_SZ * 800 * 2));

  embed_kernel<<<(T_SEQ * B_SZ * K0P + 255) / 256, 256, 0, stream>>>(x, emb, x0);
  bsum_kernel<<<13, 256, 0, stream>>>(b_l0, b_l1, bsum);
  conv_pad_kernel<<<(1600 * K0P + 255) / 256, 256, 0, stream>>>(w_ih_l0, wih0h, 1600, D_EMB, K0P, 1600 * K0P);
  conv_pad_kernel<<<(1600 * 400 + 255) / 256, 256, 0, stream>>>(w_ih_l1, wih1h, 1600, 400, 400, 1600 * 400);
  conv_pad_kernel<<<(32 * 416 + 255) / 256, 256, 0, stream>>>(lin_w, linpad, 25, 400, 416, 32 * 416);
  conv_wfrag_kernel<<<(2 * 50 * 7 * 512 + 255) / 256, 256, 0, stream>>>(w_hh_l0, wf0);
  conv_wfrag_kernel<<<(2 * 50 * 7 * 512 + 255) / 256, 256, 0, stream>>>(w_hh_l1, wf1);

  const int nch = T_SEQ / C;
  const int zN = (int)(zLen / 4);
  for (int layer = 0; layer < 2; ++layer) {
    zero_kernel<<<(zN + 255) / 256, 256, 0, stream>>>((float*)(ws + zOff), zN);
    const half_t* Ain = layer ? hbuf0 : x0;
    const half_t* Wh  = layer ? wih1h : wih0h;
    const half_t* Wf  = layer ? wf1 : wf0;
    const int Kin = layer ? 400 : K0P;
    half_t* hb = layer ? hbuf1 : hbuf0;
    for (int q = 0; q < nch; ++q) {
      xw_mfma_kernel<<<dim3(13, 2 * C, 2), 256, 0, stream>>>(Ain, Wh, bsum + layer * 1600,
                                                             chunk, Kin, C, q);
      persist4_kernel<<<dim3(8, 2), 1024, 0, stream>>>(chunk, Wf, hslab, cslab, hb, q, C);
    }
  }

  emis_mfma_kernel<<<1024, 256, 0, stream>>>(hbuf1, linpad, lin_b, em);
  crf_kernel<<<B_SZ, 64, 0, stream>>>(em, y, crf_start, crf_end, crf_trans, partial);
  reduce_kernel<<<1, 64, 0, stream>>>(partial, out);
}